// Round 2
// baseline (513.150 us; speedup 1.0000x reference)
//
#include <hip/hip_runtime.h>

#define NUM_TOKENS 8192
#define DIM 2048
#define NE 8
#define BM 256
#define BN 256
#define BK 64
#define KTILES (DIM / BK)

typedef __bf16 bf16x8 __attribute__((ext_vector_type(8)));
typedef float f32x4 __attribute__((ext_vector_type(4)));

typedef __attribute__((address_space(1))) const void* as1_cvp;
typedef __attribute__((address_space(3))) void* as3_vp;

// fp32 -> bf16 round-to-nearest-even (manual; inputs are finite)
__device__ __forceinline__ unsigned short f2bf(float f) {
  unsigned int u = __float_as_uint(f);
  unsigned int lsb = (u >> 16) & 1u;
  u += 0x7fffu + lsb;
  return (unsigned short)(u >> 16);
}
__device__ __forceinline__ float bflo(unsigned int u) {
  return __uint_as_float(u << 16);
}
__device__ __forceinline__ float bfhi(unsigned int u) {
  return __uint_as_float(u & 0xffff0000u);
}

// compiler-only memory fence: pins code motion at barrier points
#define CFENCE() asm volatile("" ::: "memory")

// ---------------- expert weights fp32 -> bf16 ----------------
__global__ __launch_bounds__(256) void convert_w_kernel(
    const float4* __restrict__ w, ushort4* __restrict__ wb) {
  int i = blockIdx.x * 256 + threadIdx.x;  // grid covers 16384*2048/4 exactly
  float4 v = w[i];
  ushort4 o;
  o.x = f2bf(v.x); o.y = f2bf(v.y); o.z = f2bf(v.z); o.w = f2bf(v.w);
  wb[i] = o;
}

// -------- gating (fp32) + x fp32->bf16; NO atomics (writes routed[t]) -------
__global__ __launch_bounds__(256) void gating_kernel(
    const float* __restrict__ x, const float* __restrict__ gw,
    const float* __restrict__ gb, unsigned short* __restrict__ xb,
    float* __restrict__ probs, int* __restrict__ routed) {
  const int wave = threadIdx.x >> 6;
  const int lane = threadIdx.x & 63;
  const int t = blockIdx.x * 4 + wave;  // one wave per token
  const float4* xrow = (const float4*)(x + (size_t)t * DIM);
  ushort4* xbrow = (ushort4*)(xb + (size_t)t * DIM);
  float acc[NE];
#pragma unroll
  for (int e = 0; e < NE; ++e) acc[e] = 0.f;
#pragma unroll
  for (int it = 0; it < DIM / (4 * 64); ++it) {  // 8 iters
    const int k4 = it * 64 + lane;
    float4 xv = xrow[k4];
    ushort4 o;
    o.x = f2bf(xv.x); o.y = f2bf(xv.y); o.z = f2bf(xv.z); o.w = f2bf(xv.w);
    xbrow[k4] = o;
#pragma unroll
    for (int e = 0; e < NE; ++e) {
      float4 wv = ((const float4*)(gw + (size_t)e * DIM))[k4];
      acc[e] += xv.x * wv.x + xv.y * wv.y + xv.z * wv.z + xv.w * wv.w;
    }
  }
#pragma unroll
  for (int e = 0; e < NE; ++e) {
#pragma unroll
    for (int off = 32; off > 0; off >>= 1)
      acc[e] += __shfl_xor(acc[e], off, 64);
  }
  if (lane == 0) {
    float p[NE];
    float mx = -1e30f;
#pragma unroll
    for (int e = 0; e < NE; ++e) {
      p[e] = acc[e] + gb[e];
      mx = fmaxf(mx, p[e]);
    }
    float s = 0.f;
#pragma unroll
    for (int e = 0; e < NE; ++e) { p[e] = __expf(p[e] - mx); s += p[e]; }
    float inv = 1.f / s;
#pragma unroll
    for (int e = 0; e < NE; ++e) p[e] *= inv;
    // top-2, ties -> lower index (matches lax.top_k)
    int e0 = 0;
#pragma unroll
    for (int e = 1; e < NE; ++e) if (p[e] > p[e0]) e0 = e;
    int e1 = (e0 == 0) ? 1 : 0;
#pragma unroll
    for (int e = 0; e < NE; ++e) if (e != e0 && p[e] > p[e1]) e1 = e;
    probs[t * 2 + 0] = p[e0];
    probs[t * 2 + 1] = p[e1];
    routed[t] = e0 | (e1 << 8);
  }
}

// ---- build per-expert token lists + COMPACT y-positions --------------------
__global__ __launch_bounds__(256) void build_lists_kernel(
    const int* __restrict__ routed, int* __restrict__ lists,
    int* __restrict__ counts, int* __restrict__ tokpos) {
  const int e = blockIdx.x;
  const int tid = threadIdx.x;
  __shared__ int sc[256];
  __shared__ int sb[256];
  const int base_t = tid * (NUM_TOKENS / 256);  // 32 tokens/thread
  int c = 0, cb = 0;
#pragma unroll 4
  for (int j = 0; j < NUM_TOKENS / 256; ++j) {
    int r = routed[base_t + j];
    int a0 = r & 0xff, a1 = (r >> 8) & 0xff;
    c += (a0 == e) + (a1 == e);
    cb += (a0 < e) + (a1 < e);
  }
  sc[tid] = c;
  sb[tid] = cb;
  __syncthreads();
  for (int ofs = 1; ofs < 256; ofs <<= 1) {  // inclusive Hillis-Steele scan
    int v = (tid >= ofs) ? sc[tid - ofs] : 0;
    int w = (tid >= ofs) ? sb[tid - ofs] : 0;
    __syncthreads();
    sc[tid] += v;
    sb[tid] += w;
    __syncthreads();
  }
  const int ebase = sb[255];  // total entries of experts < e
  int pos = sc[tid] - c;
#pragma unroll 4
  for (int j = 0; j < NUM_TOKENS / 256; ++j) {
    int t = base_t + j;
    int r = routed[t];
    if ((r & 0xff) == e) {
      lists[e * NUM_TOKENS + pos] = t;            // slot 0
      tokpos[2 * t] = ebase + pos;
      pos++;
    }
    if (((r >> 8) & 0xff) == e) {
      lists[e * NUM_TOKENS + pos] = t | 0x10000;  // slot 1
      tokpos[2 * t + 1] = ebase + pos;
      pos++;
    }
  }
  if (tid == 255) {
    counts[e] = sc[255];
    counts[8 + e] = ebase;
  }
}

// -------- grouped expert GEMM, 256x256 tile, 8-phase counted-vmcnt ---------
// Schedule ledger (per wave; all waves identical program order):
//   prologue: 8 gload_lds (K-tile 0 -> buf0)
//   iter t (buf p=t&1): issue 4 A-loads of t+1 -> p^1; s_waitcnt vmcnt(4)
//     [t's 8 oldest retired; vmcnt is in-order (m135)]; raw s_barrier
//     [=> ALL waves' t-loads landed: slabs complete cross-wave].
//     4 phases: {ds_read frags; (ph1: issue 4 B-loads of t+1); setprio(1);
//     16x mfma; setprio(0); s_barrier}.
//   Race-freedom: every store for t+1 targets p^1, whose last reads (t-1)
//   completed at the preceding phase-3 barrier -> no intra-buffer hazard.
//   vmcnt never drains to 0 in the main loop (only final tile t=31).
//   CFENCE() brackets every barrier: __builtin_amdgcn_s_barrier is IntrNoMem
//   at IR level, so without fences LLVM may legally move LDS reads / LDS-
//   writing loads across it (cross-wave race). Fences pin program order at
//   the handoff points; intra-phase scheduling freedom is untouched.
// LDS: 16B-granule XOR swizzle (granule g at row r holds global granule
// g^(r&7)); gload_lds dest linear, source pre-swizzled (rule #21).
// XCD locality: grid (8,32,8); dispatch-linear%8 == blockIdx.x == nt, so each
// XCD keeps one 1MB B-strip per expert L2-resident and walks mt; A via L3.
__global__ __launch_bounds__(512, 2) void moe_gemm_kernel(
    const unsigned short* __restrict__ xb,   // [8192,2048] bf16
    const unsigned short* __restrict__ wb,   // [16384,2048] bf16
    const float* __restrict__ eb,            // [16384]
    const float* __restrict__ probs,         // [8192,2] (fallback only)
    const int* __restrict__ lists,           // [8,8192]
    const int* __restrict__ counts,          // [0:8]=cnt, [8:16]=ybase
    unsigned short* __restrict__ y,          // [16384,2048] bf16 (use_y)
    float* __restrict__ out,                 // [8192,2048] (fallback)
    int use_y) {
  const int e = blockIdx.z;
  const int cnt = counts[e];
  const int m0 = blockIdx.y * BM;
  if (m0 >= cnt) return;
  const int n0 = blockIdx.x * BN;

  __shared__ __attribute__((aligned(16))) unsigned short As[2][BM * BK];
  __shared__ __attribute__((aligned(16))) unsigned short Bs[2][BN * BK];

  const int tid = threadIdx.x;
  const int w = tid >> 6;   // wave 0..7
  const int ln = tid & 63;
  const int sr8 = ln >> 3;                   // staging row within 8-row group
  const int sgc = ((ln & 7) ^ sr8) * 8;      // swizzled source col (elements)

  // staging sources: step rb covers rows rb*64 + w*8 + sr8 (A gathers tokens)
  const unsigned short* asrc[4];
  const unsigned short* bsrc[4];
#pragma unroll
  for (int rb = 0; rb < 4; ++rb) {
    int r = m0 + rb * 64 + w * 8 + sr8;
    int rc = r < cnt ? r : cnt - 1;  // clamp: garbage rows never stored
    int tok = lists[e * NUM_TOKENS + rc] & 0xFFFF;
    asrc[rb] = xb + (size_t)tok * DIM + sgc;
    int wr = e * DIM + n0 + rb * 64 + w * 8 + sr8;
    bsrc[rb] = wb + (size_t)wr * DIM + sgc;
  }

#define STAGE_A(buf, rb, k0)                                      \
  __builtin_amdgcn_global_load_lds(                               \
      (as1_cvp)(asrc[rb] + (k0)),                                 \
      (as3_vp)(&As[buf][((rb)*64 + w * 8) * 64]), 16, 0, 0)
#define STAGE_B(buf, rb, k0)                                      \
  __builtin_amdgcn_global_load_lds(                               \
      (as1_cvp)(bsrc[rb] + (k0)),                                 \
      (as3_vp)(&Bs[buf][((rb)*64 + w * 8) * 64]), 16, 0, 0)

#define BAR()            \
  do {                   \
    CFENCE();            \
    __builtin_amdgcn_s_barrier(); \
    CFENCE();            \
  } while (0)

  const f32x4 zero = {0.f, 0.f, 0.f, 0.f};
  f32x4 acc[8][4];
#pragma unroll
  for (int a = 0; a < 8; ++a)
#pragma unroll
    for (int b = 0; b < 4; ++b) acc[a][b] = zero;

  const int wm = w >> 2;            // wave row (0..1): 128-row strip
  const int wn = w & 3;             // wave col (0..3): 64-col strip
  const int frow = ln & 15;         // MFMA operand row
  const int csel = ln >> 4;         // granule select within k-half
  const int f7 = frow & 7;
  const int aro = (wm * 128 + frow) * 64;   // ushort offsets
  const int bro = (wn * 64 + frow) * 64;
  const int k0off = (csel ^ f7) * 8;        // kh=0 swizzled granule
  const int k1off = ((4 + csel) ^ f7) * 8;  // kh=1

  // prologue: K-tile 0 into buf 0
#pragma unroll
  for (int rb = 0; rb < 4; ++rb) STAGE_A(0, rb, 0);
#pragma unroll
  for (int rb = 0; rb < 4; ++rb) STAGE_B(0, rb, 0);

  for (int t = 0; t < KTILES; ++t) {
    const int p = t & 1;
    const int kn = (t + 1) * BK;
    if (t + 1 < KTILES) {
#pragma unroll
      for (int rb = 0; rb < 4; ++rb) STAGE_A(p ^ 1, rb, kn);
      asm volatile("s_waitcnt vmcnt(4)" ::: "memory");
    } else {
      asm volatile("s_waitcnt vmcnt(0)" ::: "memory");
    }
    BAR();
    const unsigned short* Ap = As[p];
    const unsigned short* Bp = Bs[p];
    bf16x8 af[4], bf[4];
    // ---- phase 0: kh0 x im0-3 (8 ds_read_b128) ----
#pragma unroll
    for (int i = 0; i < 4; ++i) {
      af[i] = *(const bf16x8*)(Ap + aro + i * 1024 + k0off);
      bf[i] = *(const bf16x8*)(Bp + bro + i * 1024 + k0off);
    }
    __builtin_amdgcn_s_setprio(1);
#pragma unroll
    for (int im = 0; im < 4; ++im)
#pragma unroll
      for (int in_ = 0; in_ < 4; ++in_)
        acc[im][in_] = __builtin_amdgcn_mfma_f32_16x16x32_bf16(
            af[im], bf[in_], acc[im][in_], 0, 0, 0);
    __builtin_amdgcn_s_setprio(0);
    BAR();
    // ---- phase 1: kh0 x im4-7 (4 ds_read) + issue B prefetch ----
#pragma unroll
    for (int i = 0; i < 4; ++i)
      af[i] = *(const bf16x8*)(Ap + aro + (i + 4) * 1024 + k0off);
    if (t + 1 < KTILES) {
#pragma unroll
      for (int rb = 0; rb < 4; ++rb) STAGE_B(p ^ 1, rb, kn);
    }
    __builtin_amdgcn_s_setprio(1);
#pragma unroll
    for (int im = 0; im < 4; ++im)
#pragma unroll
      for (int in_ = 0; in_ < 4; ++in_)
        acc[im + 4][in_] = __builtin_amdgcn_mfma_f32_16x16x32_bf16(
            af[im], bf[in_], acc[im + 4][in_], 0, 0, 0);
    __builtin_amdgcn_s_setprio(0);
    BAR();
    // ---- phase 2: kh1 x im0-3 ----
#pragma unroll
    for (int i = 0; i < 4; ++i) {
      af[i] = *(const bf16x8*)(Ap + aro + i * 1024 + k1off);
      bf[i] = *(const bf16x8*)(Bp + bro + i * 1024 + k1off);
    }
    __builtin_amdgcn_s_setprio(1);
#pragma unroll
    for (int im = 0; im < 4; ++im)
#pragma unroll
      for (int in_ = 0; in_ < 4; ++in_)
        acc[im][in_] = __builtin_amdgcn_mfma_f32_16x16x32_bf16(
            af[im], bf[in_], acc[im][in_], 0, 0, 0);
    __builtin_amdgcn_s_setprio(0);
    BAR();
    // ---- phase 3: kh1 x im4-7 ----
#pragma unroll
    for (int i = 0; i < 4; ++i)
      af[i] = *(const bf16x8*)(Ap + aro + (i + 4) * 1024 + k1off);
    __builtin_amdgcn_s_setprio(1);
#pragma unroll
    for (int im = 0; im < 4; ++im)
#pragma unroll
      for (int in_ = 0; in_ < 4; ++in_)
        acc[im + 4][in_] = __builtin_amdgcn_mfma_f32_16x16x32_bf16(
            af[im], bf[in_], acc[im + 4][in_], 0, 0, 0);
    __builtin_amdgcn_s_setprio(0);
    BAR();
  }
#undef STAGE_A
#undef STAGE_B
#undef BAR

  // epilogue: C/D layout col=lane&15, row=quad*4+reg (m89/m91-verified)
  const int quad = ln >> 4;
  const int col = ln & 15;
  const int ybase = counts[8 + e];
#pragma unroll
  for (int im = 0; im < 8; ++im) {
#pragma unroll
    for (int reg = 0; reg < 4; ++reg) {
      int r = m0 + wm * 128 + im * 16 + quad * 4 + reg;
      if (r >= cnt) continue;
      if (use_y) {
        unsigned short* yrow = y + (size_t)(ybase + r) * DIM;  // < 16384 rows
#pragma unroll
        for (int in_ = 0; in_ < 4; ++in_) {
          int n = n0 + wn * 64 + in_ * 16 + col;
          yrow[n] = f2bf(acc[im][in_][reg] + eb[e * DIM + n]);
        }
      } else {
        int entry = lists[e * NUM_TOKENS + r];
        int tok = entry & 0xFFFF;
        int slot = entry >> 16;
        float pw = probs[tok * 2 + slot];
        float* orow = out + (size_t)tok * DIM;
#pragma unroll
        for (int in_ = 0; in_ < 4; ++in_) {
          int n = n0 + wn * 64 + in_ * 16 + col;
          float v = acc[im][in_][reg] + eb[e * DIM + n];
          atomicAdd(orow + n, pw * v);
        }
      }
    }
  }
}

// -------- combine: out[t] = p0*y[pos0] + p1*y[pos1] (one block per token) ---
__global__ __launch_bounds__(256) void combine_kernel(
    const unsigned short* __restrict__ y, const float* __restrict__ probs,
    const int* __restrict__ tokpos, float* __restrict__ out) {
  const int t = blockIdx.x;
  const int tid = threadIdx.x;
  const int i0 = tokpos[2 * t], i1 = tokpos[2 * t + 1];
  const float p0 = probs[2 * t], p1 = probs[2 * t + 1];
  uint4 a = ((const uint4*)(y + (size_t)i0 * DIM))[tid];  // 8 bf16
  uint4 b = ((const uint4*)(y + (size_t)i1 * DIM))[tid];
  float4 o0, o1;
  o0.x = p0 * bflo(a.x) + p1 * bflo(b.x);
  o0.y = p0 * bfhi(a.x) + p1 * bfhi(b.x);
  o0.z = p0 * bflo(a.y) + p1 * bflo(b.y);
  o0.w = p0 * bfhi(a.y) + p1 * bfhi(b.y);
  o1.x = p0 * bflo(a.z) + p1 * bflo(b.z);
  o1.y = p0 * bfhi(a.z) + p1 * bfhi(b.z);
  o1.z = p0 * bflo(a.w) + p1 * bflo(b.w);
  o1.w = p0 * bfhi(a.w) + p1 * bfhi(b.w);
  float4* orow = (float4*)(out + (size_t)t * DIM);
  orow[2 * tid] = o0;
  orow[2 * tid + 1] = o1;
}

extern "C" void kernel_launch(void* const* d_in, const int* in_sizes, int n_in,
                              void* d_out, int out_size, void* d_ws, size_t ws_size,
                              hipStream_t stream) {
  const float* x  = (const float*)d_in[0];  // [8192,2048]
  const float* ew = (const float*)d_in[1];  // [16384,2048]
  const float* eb = (const float*)d_in[2];  // [16384]
  const float* gw = (const float*)d_in[3];  // [8,2048]
  const float* gb = (const float*)d_in[4];  // [8]
  float* out = (float*)d_out;               // [8192,2048] fp32
  char* p = (char*)d_ws;

  const size_t NEED = 67108864ull + 33554432ull + 67108864ull + 65536ull +
                      262144ull + 64ull + 32768ull + 65536ull;  // ~160.6 MiB
  const int use_y = (ws_size >= NEED) ? 1 : 0;

  unsigned short* wb = (unsigned short*)p; p += 67108864;
  unsigned short* xb = (unsigned short*)p; p += 33554432;
  unsigned short* y = nullptr;
  if (use_y) { y = (unsigned short*)p; p += 67108864; }
  float* probs = (float*)p; p += 65536;
  int* lists   = (int*)p;   p += 262144;
  int* counts  = (int*)p;   p += 64;
  int* routed  = (int*)p;   p += 32768;
  int* tokpos  = (int*)p;   p += 65536;

  if (!use_y)
    hipMemsetAsync(out, 0, (size_t)NUM_TOKENS * DIM * sizeof(float), stream);
  convert_w_kernel<<<(NE * DIM * DIM / 4) / 256, 256, 0, stream>>>(
      (const float4*)ew, (ushort4*)wb);
  gating_kernel<<<NUM_TOKENS / 4, 256, 0, stream>>>(x, gw, gb, xb, probs,
                                                    routed);
  build_lists_kernel<<<NE, 256, 0, stream>>>(routed, lists, counts, tokpos);
  moe_gemm_kernel<<<dim3(DIM / BN, NUM_TOKENS / BM, NE), 512, 0, stream>>>(
      xb, wb, eb, probs, lists, counts, y, out, use_y);
  if (use_y)
    combine_kernel<<<NUM_TOKENS, 256, 0, stream>>>(y, probs, tokpos, out);
}